// Round 3
// baseline (386.469 us; speedup 1.0000x reference)
//
#include <hip/hip_runtime.h>

#define HIDDEN 768
#define NH 12
#define DH 64
#define BB 4
#define TT 2048
#define MTOT (BB * TT)  // 8192

typedef __bf16 bf16x8 __attribute__((ext_vector_type(8)));
typedef short s16x8 __attribute__((ext_vector_type(8)));
typedef float f32x4 __attribute__((ext_vector_type(4)));

__device__ __forceinline__ unsigned short f2b(float f) {
    unsigned u = __builtin_bit_cast(unsigned, f);
    u += 0x7fffu + ((u >> 16) & 1u);  // RNE
    return (unsigned short)(u >> 16);
}

typedef const __attribute__((address_space(1))) unsigned int* gas_ptr;
typedef __attribute__((address_space(3))) unsigned int* las_ptr;
__device__ __forceinline__ void gload16(const void* g, void* l) {
    __builtin_amdgcn_global_load_lds((gas_ptr)(uintptr_t)g, (las_ptr)(uintptr_t)l, 16, 0, 0);
}

// ---------------- fp32 -> bf16 conversion (fused scale) ----------------
__global__ __launch_bounds__(256) void cvt_kernel(const float* __restrict__ in,
                                                  unsigned short* __restrict__ out,
                                                  int n8, float scale) {
    int i = blockIdx.x * 256 + threadIdx.x;
    if (i >= n8) return;
    const float4* p = (const float4*)in + (size_t)i * 2;
    float4 a = p[0], b = p[1];
    union { uint4 u; unsigned short s[8]; } t;
    t.s[0] = f2b(a.x * scale); t.s[1] = f2b(a.y * scale);
    t.s[2] = f2b(a.z * scale); t.s[3] = f2b(a.w * scale);
    t.s[4] = f2b(b.x * scale); t.s[5] = f2b(b.y * scale);
    t.s[6] = f2b(b.z * scale); t.s[7] = f2b(b.w * scale);
    *((uint4*)out + i) = t.u;
}

// ---------------- GEMM core: C[M,N] = A[M,K] @ B[N,K]^T, 64x128 tile ----------------
template <int OUTF>
__device__ __forceinline__ void gemm_body(const unsigned short* __restrict__ A,
                                          const unsigned short* __restrict__ Bm,
                                          float* __restrict__ Cf,
                                          unsigned short* __restrict__ Cb,
                                          int M, int N, int K, int mBase, int nBase) {
    __shared__ __align__(16) unsigned short Al[8][64][8];
    __shared__ __align__(16) unsigned short Bl[8][128][8];
    const int tid = threadIdx.x;
    const int lane = tid & 63;
    const int wave = tid >> 6;
    const int quad = lane >> 4;
    const int l16 = lane & 15;
    const int mw = (wave >> 1) * 32;
    const int nw = (wave & 1) * 64;

    f32x4 acc[2][4];
#pragma unroll
    for (int mt = 0; mt < 2; ++mt)
#pragma unroll
        for (int nt = 0; nt < 4; ++nt) acc[mt][nt] = (f32x4){0.f, 0.f, 0.f, 0.f};

    const int nkb = K >> 6;
    for (int kb = 0; kb < nkb; ++kb) {
        const int k0 = kb << 6;
#pragma unroll
        for (int i = 0; i < 2; ++i) {
            int c = wave * 2 + i;
            gload16(&A[(size_t)(mBase + lane) * K + k0 + c * 8], &Al[c][0][0]);
        }
#pragma unroll
        for (int j = 0; j < 4; ++j) {
            int c = wave * 2 + (j >> 1);
            int n0 = (j & 1) * 64;
            gload16(&Bm[(size_t)(nBase + n0 + lane) * K + k0 + c * 8], &Bl[c][n0][0]);
        }
        __syncthreads();
#pragma unroll
        for (int ks = 0; ks < 2; ++ks) {
            bf16x8 af[2], bf[4];
#pragma unroll
            for (int mt = 0; mt < 2; ++mt)
                af[mt] = *(const bf16x8*)&Al[ks * 4 + quad][mw + mt * 16 + l16][0];
#pragma unroll
            for (int nt = 0; nt < 4; ++nt)
                bf[nt] = *(const bf16x8*)&Bl[ks * 4 + quad][nw + nt * 16 + l16][0];
#pragma unroll
            for (int mt = 0; mt < 2; ++mt)
#pragma unroll
                for (int nt = 0; nt < 4; ++nt)
                    acc[mt][nt] = __builtin_amdgcn_mfma_f32_16x16x32_bf16(
                        af[mt], bf[nt], acc[mt][nt], 0, 0, 0);
        }
        __syncthreads();
    }

#pragma unroll
    for (int mt = 0; mt < 2; ++mt)
#pragma unroll
        for (int nt = 0; nt < 4; ++nt)
#pragma unroll
            for (int r = 0; r < 4; ++r) {
                int row = mBase + mw + mt * 16 + quad * 4 + r;
                int col = nBase + nw + nt * 16 + l16;
                float v = acc[mt][nt][r];
                if (OUTF)
                    Cf[(size_t)row * N + col] = v;
                else
                    Cb[(size_t)row * N + col] = f2b(v);
            }
}

// Fused QKV: blockIdx.y = wsel*6 + nb; weights/outputs contiguous in ws.
__global__ __launch_bounds__(256) void gemm_qkv(const unsigned short* __restrict__ A,
                                                const unsigned short* __restrict__ W0,
                                                unsigned short* __restrict__ C0) {
    const int wsel = blockIdx.y / 6;
    const int nb = blockIdx.y % 6;
    const unsigned short* Bm = W0 + (size_t)wsel * HIDDEN * HIDDEN;
    unsigned short* Cb = C0 + (size_t)wsel * MTOT * HIDDEN;
    gemm_body<0>(A, Bm, nullptr, Cb, MTOT, HIDDEN, HIDDEN, blockIdx.x * 64, nb * 128);
}

__global__ __launch_bounds__(256) void gemm_out(const unsigned short* __restrict__ A,
                                                const unsigned short* __restrict__ Bm,
                                                float* __restrict__ Cf) {
    gemm_body<1>(A, Bm, Cf, nullptr, MTOT, HIDDEN, HIDDEN, blockIdx.x * 64, blockIdx.y * 128);
}

// ---------------- V transpose: [8192][768] -> [768][8192] ----------------
__global__ __launch_bounds__(256) void vt_kernel(const unsigned short* __restrict__ in,
                                                 unsigned short* __restrict__ out) {
    __shared__ unsigned short T[64][73];
    const int tid = threadIdx.x;
    const int r0 = blockIdx.x * 64;
    const int c0 = blockIdx.y * 64;
#pragma unroll
    for (int p = 0; p < 2; ++p) {
        int idx = p * 256 + tid;
        int r = idx >> 3, c = idx & 7;
        union { uint4 u; unsigned short s[8]; } t;
        t.u = *(const uint4*)&in[(size_t)(r0 + r) * HIDDEN + c0 + c * 8];
#pragma unroll
        for (int e = 0; e < 8; ++e) T[r][c * 8 + e] = t.s[e];
    }
    __syncthreads();
#pragma unroll
    for (int p = 0; p < 2; ++p) {
        int idx = p * 256 + tid;
        int cc = idx >> 3, rc = idx & 7;
        union { uint4 u; unsigned short s[8]; } t;
#pragma unroll
        for (int e = 0; e < 8; ++e) t.s[e] = T[rc * 8 + e][cc];
        *(uint4*)&out[(size_t)(c0 + cc) * MTOT + r0 + rc * 8] = t.u;
    }
}

// ---------------- Flash attention: barrier-free ----------------
// 4 waves x 32 q-rows. K/V fragments loaded DIRECTLY from global (b128, 16
// cachelines/inst — same as coalesced; L1/L2 serve the reuse). P is wave-
// private LDS (stride 68: store banks = quad*8 + l16/2, conflict-free); the
// C->A layout round-trip needs only same-wave lgkmcnt, NO barriers anywhere.
__global__ __launch_bounds__(256) void attn_kernel(const unsigned short* __restrict__ Qg,
                                                   const unsigned short* __restrict__ Kg,
                                                   const unsigned short* __restrict__ VTg,
                                                   unsigned short* __restrict__ Ctx) {
    __shared__ __align__(16) unsigned short Pl[4][32][68];
    const int tid = threadIdx.x;
    const int lane = tid & 63;
    const int wave = tid >> 6;
    const int quad = lane >> 4;
    const int l16 = lane & 15;
    const int qt = blockIdx.x;  // 0..15
    const int bh = blockIdx.y;  // 0..47
    const int b = bh / NH, h = bh % NH;
    const int qrow0 = b * TT + qt * 128;
    const int col0 = h * DH;

    // Per-lane fragment base pointers (K rows / V^T rows), bumped per tile.
    const unsigned short* Kp = Kg + (size_t)(b * TT + l16) * HIDDEN + col0 + quad * 8;
    const unsigned short* Vp = VTg + (size_t)(col0 + l16) * MTOT + b * TT + quad * 8;

    // Q fragments resident all kernel (log2e/8 pre-folded into w_q)
    bf16x8 qf[2][2];
#pragma unroll
    for (int mt = 0; mt < 2; ++mt)
#pragma unroll
        for (int ks = 0; ks < 2; ++ks)
            qf[mt][ks] = *(const bf16x8*)&Qg[(size_t)(qrow0 + wave * 32 + mt * 16 + l16) * HIDDEN +
                                             col0 + ks * 32 + quad * 8];

    s16x8 osv;
#pragma unroll
    for (int e = 0; e < 8; ++e) osv[e] = 0x3F80;  // bf16 1.0
    const bf16x8 ones = __builtin_bit_cast(bf16x8, osv);

    f32x4 o[2][4];
    f32x4 lacc[2];
#pragma unroll
    for (int mt = 0; mt < 2; ++mt) {
        lacc[mt] = (f32x4){0.f, 0.f, 0.f, 0.f};
#pragma unroll
        for (int nt = 0; nt < 4; ++nt) o[mt][nt] = (f32x4){0.f, 0.f, 0.f, 0.f};
    }

    for (int kt = 0; kt < TT / 64; ++kt) {
        // Issue all 16 fragment loads up front; QK waits on kf, PV's vf
        // arrives during softmax. No LDS staging, no barriers.
        bf16x8 kf[2][4], vf[2][4];
#pragma unroll
        for (int ks = 0; ks < 2; ++ks)
#pragma unroll
            for (int nt = 0; nt < 4; ++nt)
                kf[ks][nt] = *(const bf16x8*)(Kp + (size_t)(nt * 16) * HIDDEN + ks * 32);
#pragma unroll
        for (int ks = 0; ks < 2; ++ks)
#pragma unroll
            for (int nt = 0; nt < 4; ++nt)
                vf[ks][nt] = *(const bf16x8*)(Vp + (size_t)(nt * 16) * MTOT + ks * 32);

        // S = Q' K^T (log2 units)
        f32x4 s[2][4];
#pragma unroll
        for (int mt = 0; mt < 2; ++mt)
#pragma unroll
            for (int nt = 0; nt < 4; ++nt) s[mt][nt] = (f32x4){0.f, 0.f, 0.f, 0.f};
#pragma unroll
        for (int ks = 0; ks < 2; ++ks)
#pragma unroll
            for (int mt = 0; mt < 2; ++mt)
#pragma unroll
                for (int nt = 0; nt < 4; ++nt)
                    s[mt][nt] = __builtin_amdgcn_mfma_f32_16x16x32_bf16(qf[mt][ks], kf[ks][nt],
                                                                        s[mt][nt], 0, 0, 0);

        // P = exp2(S) -> bf16 -> wave-private LDS (row-sum via MFMA uses the
        // same truncated values: quantization bias cancels in normalization)
#pragma unroll
        for (int mt = 0; mt < 2; ++mt) {
            int row0 = mt * 16 + quad * 4;
#pragma unroll
            for (int nt = 0; nt < 4; ++nt) {
                int col = nt * 16 + l16;
#pragma unroll
                for (int r = 0; r < 4; ++r) {
                    float pv = __builtin_amdgcn_exp2f(s[mt][nt][r]);
                    Pl[wave][row0 + r][col] =
                        (unsigned short)(__builtin_bit_cast(unsigned, pv) >> 16);
                }
            }
        }

        // O += P V ; l += P . 1   (same-wave LDS round trip: lgkmcnt only)
#pragma unroll
        for (int ks = 0; ks < 2; ++ks) {
            bf16x8 pf[2];
#pragma unroll
            for (int mt = 0; mt < 2; ++mt)
                pf[mt] = *(const bf16x8*)&Pl[wave][mt * 16 + l16][ks * 32 + quad * 8];
#pragma unroll
            for (int mt = 0; mt < 2; ++mt)
                lacc[mt] = __builtin_amdgcn_mfma_f32_16x16x32_bf16(pf[mt], ones, lacc[mt], 0, 0, 0);
#pragma unroll
            for (int mt = 0; mt < 2; ++mt)
#pragma unroll
                for (int nt = 0; nt < 4; ++nt)
                    o[mt][nt] = __builtin_amdgcn_mfma_f32_16x16x32_bf16(pf[mt], vf[ks][nt],
                                                                        o[mt][nt], 0, 0, 0);
        }

        Kp += 64 * HIDDEN;
        Vp += 64;
    }

    // Epilogue: normalize by MFMA row sums (C-layout, no shuffles)
#pragma unroll
    for (int mt = 0; mt < 2; ++mt)
#pragma unroll
        for (int r = 0; r < 4; ++r) {
            float inv = __builtin_amdgcn_rcpf(lacc[mt][r]);
            int row = qrow0 + wave * 32 + mt * 16 + quad * 4 + r;
#pragma unroll
            for (int nt = 0; nt < 4; ++nt)
                Ctx[(size_t)row * HIDDEN + col0 + nt * 16 + l16] = f2b(o[mt][nt][r] * inv);
        }
}

// ---------------- launch ----------------
extern "C" void kernel_launch(void* const* d_in, const int* in_sizes, int n_in,
                              void* d_out, int out_size, void* d_ws, size_t ws_size,
                              hipStream_t stream) {
    const float* x = (const float*)d_in[0];
    const float* wq = (const float*)d_in[1];
    const float* wk = (const float*)d_in[2];
    const float* wv = (const float*)d_in[3];
    const float* wo = (const float*)d_in[4];
    float* out = (float*)d_out;

    const size_t NX = (size_t)MTOT * HIDDEN;
    const size_t NW = (size_t)HIDDEN * HIDDEN;
    unsigned short* ws = (unsigned short*)d_ws;
    unsigned short* xb = ws;
    unsigned short* wqb = xb + NX;   // wq, wk, wv contiguous (fused GEMM indexes them)
    unsigned short* wkb = wqb + NW;
    unsigned short* wvb = wkb + NW;
    unsigned short* wob = wvb + NW;
    unsigned short* qb = wob + NW;   // q, k, v contiguous (fused GEMM indexes them)
    unsigned short* kb = qb + NX;
    unsigned short* vb = kb + NX;
    unsigned short* vtb = vb + NX;
    unsigned short* cb = vb;  // alias: vb dead after vt_kernel

    const float SC2 = 0.18033688011112042f;  // log2(e)/sqrt(64)

    cvt_kernel<<<(int)(NX / 8 / 256), 256, 0, stream>>>(x, xb, (int)(NX / 8), 1.0f);
    cvt_kernel<<<(int)(NW / 8 / 256), 256, 0, stream>>>(wq, wqb, (int)(NW / 8), SC2);
    cvt_kernel<<<(int)(NW / 8 / 256), 256, 0, stream>>>(wk, wkb, (int)(NW / 8), 1.0f);
    cvt_kernel<<<(int)(NW / 8 / 256), 256, 0, stream>>>(wv, wvb, (int)(NW / 8), 1.0f);
    cvt_kernel<<<(int)(NW / 8 / 256), 256, 0, stream>>>(wo, wob, (int)(NW / 8), 1.0f);

    gemm_qkv<<<dim3(MTOT / 64, 18), 256, 0, stream>>>(xb, wqb, qb);

    vt_kernel<<<dim3(MTOT / 64, HIDDEN / 64), 256, 0, stream>>>(vb, vtb);

    attn_kernel<<<dim3(TT / 128, BB * NH), 256, 0, stream>>>(qb, kb, vtb, cb);

    gemm_out<<<dim3(MTOT / 64, HIDDEN / 128), 256, 0, stream>>>(cb, wob, out);
}

// Round 5
// 229.741 us; speedup vs baseline: 1.6822x; 1.6822x over previous
//
#include <hip/hip_runtime.h>

#define HIDDEN 768
#define NH 12
#define DH 64
#define BB 4
#define TT 2048
#define MTOT (BB * TT)  // 8192

typedef __bf16 bf16x8 __attribute__((ext_vector_type(8)));
typedef short s16x8 __attribute__((ext_vector_type(8)));
typedef float f32x4 __attribute__((ext_vector_type(4)));

__device__ __forceinline__ unsigned short f2b(float f) {
    unsigned u = __builtin_bit_cast(unsigned, f);
    u += 0x7fffu + ((u >> 16) & 1u);  // RNE
    return (unsigned short)(u >> 16);
}

typedef const __attribute__((address_space(1))) unsigned int* gas_ptr;
typedef __attribute__((address_space(3))) unsigned int* las_ptr;
__device__ __forceinline__ void gload16(const void* g, void* l) {
    // DMA: lane i lands at (wave-uniform) lds base + i*16.
    __builtin_amdgcn_global_load_lds((gas_ptr)(uintptr_t)g, (las_ptr)(uintptr_t)l, 16, 0, 0);
}

// ---------------- fused fp32->bf16 for all 5 tensors (1 launch) ----------------
// Region boundaries are block-aligned (NX/8 and NW/8 divisible by 256): no divergence.
__global__ __launch_bounds__(256) void cvt_all(const float* __restrict__ x,
                                               const float* __restrict__ wq,
                                               const float* __restrict__ wk,
                                               const float* __restrict__ wv,
                                               const float* __restrict__ wo,
                                               unsigned short* __restrict__ out) {
    const size_t NX8 = (size_t)MTOT * HIDDEN / 8;
    const size_t NW8 = (size_t)HIDDEN * HIDDEN / 8;
    size_t i = (size_t)blockIdx.x * 256 + threadIdx.x;
    const float* src;
    size_t off = i;
    float scale = 1.0f;
    if (i < NX8) { src = x; }
    else if (i < NX8 + NW8) { src = wq; off = i - NX8; scale = 0.18033688011112042f; }  // log2e/8
    else if (i < NX8 + 2 * NW8) { src = wk; off = i - NX8 - NW8; }
    else if (i < NX8 + 3 * NW8) { src = wv; off = i - NX8 - 2 * NW8; }
    else { src = wo; off = i - NX8 - 3 * NW8; }
    const float4* p = (const float4*)src + off * 2;
    float4 a = p[0], b = p[1];
    union { uint4 u; unsigned short s[8]; } t;
    t.s[0] = f2b(a.x * scale); t.s[1] = f2b(a.y * scale);
    t.s[2] = f2b(a.z * scale); t.s[3] = f2b(a.w * scale);
    t.s[4] = f2b(b.x * scale); t.s[5] = f2b(b.y * scale);
    t.s[6] = f2b(b.z * scale); t.s[7] = f2b(b.w * scale);
    ((uint4*)out)[i] = t.u;
}

// ---------------- GEMM: C[M,N] = A[M,768] @ B[N,768]^T ----------------
// 128x128 tile, 4 waves 2x2 (64x64 each, 4x4 MFMA tiles). Double-buffered
// global_load_lds staging with XOR chunk swizzle (LDS[row][c]=glob[row][c^(row&7)]):
// fragment ds_read_b128 hits all 32 banks with 2-way alias (free, m136).
// One __syncthreads/iter; prefetch issued right after it -> the barrier's
// vmcnt(0) only drains loads issued a whole compute phase earlier.
template <int OUTF>
__device__ __forceinline__ void gemm_body(const unsigned short* __restrict__ A,
                                          const unsigned short* __restrict__ Bm,
                                          float* __restrict__ Cf,
                                          unsigned short* __restrict__ Cb,
                                          int mBase, int nBase, int N) {
    __shared__ __align__(16) unsigned short Al[2][128][64];
    __shared__ __align__(16) unsigned short Bl[2][128][64];
    const int tid = threadIdx.x;
    const int lane = tid & 63;
    const int wave = tid >> 6;
    const int quad = lane >> 4;
    const int l16 = lane & 15;
    const int mw = (wave >> 1) * 64;
    const int nw = (wave & 1) * 64;
    const int srow = wave * 32 + (lane >> 3);
    const int swiz = ((lane & 7) ^ (lane >> 3)) * 8;
    const unsigned short* Asrc = A + (size_t)(mBase + srow) * HIDDEN + swiz;
    const unsigned short* Bsrc = Bm + (size_t)(nBase + srow) * HIDDEN + swiz;

    f32x4 acc[4][4];
#pragma unroll
    for (int mt = 0; mt < 4; ++mt)
#pragma unroll
        for (int nt = 0; nt < 4; ++nt) acc[mt][nt] = (f32x4){0.f, 0.f, 0.f, 0.f};

    auto stage = [&](int buf, int kb) {
#pragma unroll
        for (int i = 0; i < 4; ++i) {
            gload16(Asrc + (size_t)i * 8 * HIDDEN + kb * 64, &Al[buf][wave * 32 + i * 8][0]);
            gload16(Bsrc + (size_t)i * 8 * HIDDEN + kb * 64, &Bl[buf][wave * 32 + i * 8][0]);
        }
    };

    stage(0, 0);
    for (int kb = 0; kb < HIDDEN / 64; ++kb) {
        __syncthreads();
        if (kb + 1 < HIDDEN / 64) stage((kb + 1) & 1, kb + 1);
        const int buf = kb & 1;
#pragma unroll
        for (int ks = 0; ks < 2; ++ks) {
            const int cc = ((ks * 4 + quad) ^ (l16 & 7)) * 8;
            bf16x8 af[4], bf[4];
#pragma unroll
            for (int t = 0; t < 4; ++t) {
                af[t] = *(const bf16x8*)&Al[buf][mw + t * 16 + l16][cc];
                bf[t] = *(const bf16x8*)&Bl[buf][nw + t * 16 + l16][cc];
            }
#pragma unroll
            for (int mt = 0; mt < 4; ++mt)
#pragma unroll
                for (int nt = 0; nt < 4; ++nt)
                    acc[mt][nt] = __builtin_amdgcn_mfma_f32_16x16x32_bf16(
                        af[mt], bf[nt], acc[mt][nt], 0, 0, 0);
        }
    }

#pragma unroll
    for (int mt = 0; mt < 4; ++mt)
#pragma unroll
        for (int nt = 0; nt < 4; ++nt)
#pragma unroll
            for (int r = 0; r < 4; ++r) {
                int row = mBase + mw + mt * 16 + quad * 4 + r;
                int col = nBase + nw + nt * 16 + l16;
                float v = acc[mt][nt][r];
                if (OUTF)
                    Cf[(size_t)row * N + col] = v;
                else
                    Cb[(size_t)row * N + col] = f2b(v);
            }
}

// Fused QKV: blockIdx.x = wsel*6 + nb (x-fast => consecutive blocks share A tile).
__global__ __launch_bounds__(256) void gemm_qkv(const unsigned short* __restrict__ A,
                                                const unsigned short* __restrict__ W0,
                                                unsigned short* __restrict__ C0) {
    const int wsel = blockIdx.x / 6;
    const int nb = blockIdx.x % 6;
    gemm_body<0>(A, W0 + (size_t)wsel * HIDDEN * HIDDEN, nullptr,
                 C0 + (size_t)wsel * MTOT * HIDDEN, blockIdx.y * 128, nb * 128, HIDDEN);
}

__global__ __launch_bounds__(256) void gemm_out(const unsigned short* __restrict__ A,
                                                const unsigned short* __restrict__ Bm,
                                                float* __restrict__ Cf) {
    gemm_body<1>(A, Bm, Cf, nullptr, blockIdx.y * 128, blockIdx.x * 128, HIDDEN);
}

// ---------------- V transpose: [8192][768] -> [768][8192] ----------------
__global__ __launch_bounds__(256) void vt_kernel(const unsigned short* __restrict__ in,
                                                 unsigned short* __restrict__ out) {
    __shared__ unsigned short T[64][73];
    const int tid = threadIdx.x;
    const int r0 = blockIdx.x * 64;
    const int c0 = blockIdx.y * 64;
#pragma unroll
    for (int p = 0; p < 2; ++p) {
        int idx = p * 256 + tid;
        int r = idx >> 3, c = idx & 7;
        union { uint4 u; unsigned short s[8]; } t;
        t.u = *(const uint4*)&in[(size_t)(r0 + r) * HIDDEN + c0 + c * 8];
#pragma unroll
        for (int e = 0; e < 8; ++e) T[r][c * 8 + e] = t.s[e];
    }
    __syncthreads();
#pragma unroll
    for (int p = 0; p < 2; ++p) {
        int idx = p * 256 + tid;
        int cc = idx >> 3, rc = idx & 7;
        union { uint4 u; unsigned short s[8]; } t;
#pragma unroll
        for (int e = 0; e < 8; ++e) t.s[e] = T[rc * 8 + e][cc];
        *(uint4*)&out[(size_t)(c0 + cc) * MTOT + r0 + rc * 8] = t.u;
    }
}

// ---------------- Flash attention ----------------
// 4 waves x 32 q-rows per block; K/V double-buffered via swizzled
// global_load_lds (1 barrier/tile, prefetch in flight across it); P wave-
// private stride-68 (0 conflicts, measured r3); row sums by MFMA-with-ones.
__global__ __launch_bounds__(256) void attn_kernel(const unsigned short* __restrict__ Qg,
                                                   const unsigned short* __restrict__ Kg,
                                                   const unsigned short* __restrict__ VTg,
                                                   unsigned short* __restrict__ Ctx) {
    __shared__ __align__(16) unsigned short Kl[2][64][64];
    __shared__ __align__(16) unsigned short Vl[2][64][64];
    __shared__ __align__(16) unsigned short Pl[4][32][68];
    const int tid = threadIdx.x;
    const int lane = tid & 63;
    const int wave = tid >> 6;
    const int quad = lane >> 4;
    const int l16 = lane & 15;
    const int qt = blockIdx.x;  // 0..15
    const int bh = blockIdx.y;  // 0..47
    const int b = bh / NH, h = bh % NH;
    const int qrow0 = b * TT + qt * 128;
    const int col0 = h * DH;

    const int srow = wave * 16 + (lane >> 3);
    const int swiz = ((lane & 7) ^ (lane >> 3)) * 8;
    const unsigned short* Ksrc = Kg + (size_t)(b * TT + srow) * HIDDEN + col0 + swiz;
    const unsigned short* Vsrc = VTg + (size_t)(col0 + srow) * MTOT + b * TT + swiz;

    auto stage = [&](int buf, int kt) {
#pragma unroll
        for (int i = 0; i < 2; ++i) {
            // K tile advance = 64 KEYS = rows of Kg  (r4 bug: was +kt*64 columns)
            gload16(Ksrc + (size_t)(kt * 64 + i * 8) * HIDDEN, &Kl[buf][wave * 16 + i * 8][0]);
            // V^T tile advance = 64 keys = columns of VTg
            gload16(Vsrc + (size_t)(i * 8) * MTOT + kt * 64, &Vl[buf][wave * 16 + i * 8][0]);
        }
    };

    // Q fragments resident all kernel (log2e/8 pre-folded into w_q)
    bf16x8 qf[2][2];
#pragma unroll
    for (int mt = 0; mt < 2; ++mt)
#pragma unroll
        for (int ks = 0; ks < 2; ++ks)
            qf[mt][ks] = *(const bf16x8*)&Qg[(size_t)(qrow0 + wave * 32 + mt * 16 + l16) * HIDDEN +
                                             col0 + ks * 32 + quad * 8];

    s16x8 osv;
#pragma unroll
    for (int e = 0; e < 8; ++e) osv[e] = 0x3F80;  // bf16 1.0
    const bf16x8 ones = __builtin_bit_cast(bf16x8, osv);

    f32x4 o[2][4];
    f32x4 lacc[2];
#pragma unroll
    for (int mt = 0; mt < 2; ++mt) {
        lacc[mt] = (f32x4){0.f, 0.f, 0.f, 0.f};
#pragma unroll
        for (int nt = 0; nt < 4; ++nt) o[mt][nt] = (f32x4){0.f, 0.f, 0.f, 0.f};
    }

    stage(0, 0);
    for (int kt = 0; kt < TT / 64; ++kt) {
        __syncthreads();  // drains only loads issued a full compute phase ago
        if (kt + 1 < TT / 64) stage((kt + 1) & 1, kt + 1);
        const int buf = kt & 1;

        // S = Q' K^T (log2 units)
        f32x4 s[2][4];
#pragma unroll
        for (int mt = 0; mt < 2; ++mt)
#pragma unroll
            for (int nt = 0; nt < 4; ++nt) s[mt][nt] = (f32x4){0.f, 0.f, 0.f, 0.f};
#pragma unroll
        for (int ks = 0; ks < 2; ++ks) {
            const int cc = ((ks * 4 + quad) ^ (l16 & 7)) * 8;
            bf16x8 kf[4];
#pragma unroll
            for (int nt = 0; nt < 4; ++nt)
                kf[nt] = *(const bf16x8*)&Kl[buf][nt * 16 + l16][cc];
#pragma unroll
            for (int mt = 0; mt < 2; ++mt)
#pragma unroll
                for (int nt = 0; nt < 4; ++nt)
                    s[mt][nt] = __builtin_amdgcn_mfma_f32_16x16x32_bf16(qf[mt][ks], kf[nt],
                                                                        s[mt][nt], 0, 0, 0);
        }

        // P = exp2(S) -> bf16 -> wave-private LDS (row sums use the SAME
        // truncated values: quantization bias cancels in normalization)
#pragma unroll
        for (int mt = 0; mt < 2; ++mt) {
            int row0 = mt * 16 + quad * 4;
#pragma unroll
            for (int nt = 0; nt < 4; ++nt) {
                int col = nt * 16 + l16;
#pragma unroll
                for (int r = 0; r < 4; ++r) {
                    float pv = __builtin_amdgcn_exp2f(s[mt][nt][r]);
                    Pl[wave][row0 + r][col] =
                        (unsigned short)(__builtin_bit_cast(unsigned, pv) >> 16);
                }
            }
        }

        // O += P V ; l += P . 1   (same-wave LDS round trip: lgkmcnt only)
#pragma unroll
        for (int ks = 0; ks < 2; ++ks) {
            const int cc = ((ks * 4 + quad) ^ (l16 & 7)) * 8;
            bf16x8 pf[2], vf[4];
#pragma unroll
            for (int mt = 0; mt < 2; ++mt)
                pf[mt] = *(const bf16x8*)&Pl[wave][mt * 16 + l16][ks * 32 + quad * 8];
#pragma unroll
            for (int nt = 0; nt < 4; ++nt)
                vf[nt] = *(const bf16x8*)&Vl[buf][nt * 16 + l16][cc];
#pragma unroll
            for (int mt = 0; mt < 2; ++mt)
                lacc[mt] = __builtin_amdgcn_mfma_f32_16x16x32_bf16(pf[mt], ones, lacc[mt], 0, 0, 0);
#pragma unroll
            for (int mt = 0; mt < 2; ++mt)
#pragma unroll
                for (int nt = 0; nt < 4; ++nt)
                    o[mt][nt] = __builtin_amdgcn_mfma_f32_16x16x32_bf16(pf[mt], vf[nt],
                                                                        o[mt][nt], 0, 0, 0);
        }
    }

    // Epilogue: normalize by MFMA row sums (C-layout, no shuffles)
#pragma unroll
    for (int mt = 0; mt < 2; ++mt)
#pragma unroll
        for (int r = 0; r < 4; ++r) {
            float inv = __builtin_amdgcn_rcpf(lacc[mt][r]);
            int row = qrow0 + wave * 32 + mt * 16 + quad * 4 + r;
#pragma unroll
            for (int nt = 0; nt < 4; ++nt)
                Ctx[(size_t)row * HIDDEN + col0 + nt * 16 + l16] = f2b(o[mt][nt][r] * inv);
        }
}

// ---------------- launch ----------------
extern "C" void kernel_launch(void* const* d_in, const int* in_sizes, int n_in,
                              void* d_out, int out_size, void* d_ws, size_t ws_size,
                              hipStream_t stream) {
    const float* x = (const float*)d_in[0];
    const float* wq = (const float*)d_in[1];
    const float* wk = (const float*)d_in[2];
    const float* wv = (const float*)d_in[3];
    const float* wo = (const float*)d_in[4];
    float* out = (float*)d_out;

    const size_t NX = (size_t)MTOT * HIDDEN;
    const size_t NW = (size_t)HIDDEN * HIDDEN;
    unsigned short* ws = (unsigned short*)d_ws;
    unsigned short* xb = ws;            // cvt_all writes x|wq|wk|wv|wo contiguously here
    unsigned short* wqb = xb + NX;
    unsigned short* wob = wqb + 3 * NW;
    unsigned short* qb = wob + NW;      // q|k|v contiguous (fused GEMM output)
    unsigned short* kb = qb + NX;
    unsigned short* vb = kb + NX;
    unsigned short* vtb = vb + NX;
    unsigned short* cb = vb;  // alias: vb dead after vt_kernel

    cvt_all<<<(int)((NX + 4 * NW) / 8 / 256), 256, 0, stream>>>(x, wq, wk, wv, wo, xb);

    gemm_qkv<<<dim3(18, MTOT / 128), 256, 0, stream>>>(xb, wqb, qb);

    vt_kernel<<<dim3(MTOT / 64, HIDDEN / 64), 256, 0, stream>>>(vb, vtb);

    attn_kernel<<<dim3(TT / 128, BB * NH), 256, 0, stream>>>(qb, kb, vtb, cb);

    gemm_out<<<dim3(6, MTOT / 128), 256, 0, stream>>>(cb, wob, out);
}

// Round 6
// 222.330 us; speedup vs baseline: 1.7383x; 1.0333x over previous
//
#include <hip/hip_runtime.h>

#define HIDDEN 768
#define NH 12
#define DH 64
#define BB 4
#define TT 2048
#define MTOT (BB * TT)  // 8192

typedef __bf16 bf16x8 __attribute__((ext_vector_type(8)));
typedef short s16x8 __attribute__((ext_vector_type(8)));
typedef float f32x4 __attribute__((ext_vector_type(4)));

__device__ __forceinline__ unsigned short f2b(float f) {
    unsigned u = __builtin_bit_cast(unsigned, f);
    u += 0x7fffu + ((u >> 16) & 1u);  // RNE
    return (unsigned short)(u >> 16);
}

// pack two f32 -> (bf16(lo)=trunc(a), bf16(hi)=trunc(b)) in one v_perm_b32
__device__ __forceinline__ unsigned pack_bf16(float a, float b) {
    return __builtin_amdgcn_perm(__builtin_bit_cast(unsigned, b),
                                 __builtin_bit_cast(unsigned, a), 0x07060302u);
}

typedef const __attribute__((address_space(1))) unsigned int* gas_ptr;
typedef __attribute__((address_space(3))) unsigned int* las_ptr;
__device__ __forceinline__ void gload16(const void* g, void* l) {
    // DMA: lane i lands at (wave-uniform) lds base + i*16.
    __builtin_amdgcn_global_load_lds((gas_ptr)(uintptr_t)g, (las_ptr)(uintptr_t)l, 16, 0, 0);
}

// ---------------- fused fp32->bf16 for all 5 tensors (1 launch) ----------------
__global__ __launch_bounds__(256) void cvt_all(const float* __restrict__ x,
                                               const float* __restrict__ wq,
                                               const float* __restrict__ wk,
                                               const float* __restrict__ wv,
                                               const float* __restrict__ wo,
                                               unsigned short* __restrict__ out) {
    const size_t NX8 = (size_t)MTOT * HIDDEN / 8;
    const size_t NW8 = (size_t)HIDDEN * HIDDEN / 8;
    size_t i = (size_t)blockIdx.x * 256 + threadIdx.x;
    const float* src;
    size_t off = i;
    float scale = 1.0f;
    if (i < NX8) { src = x; }
    else if (i < NX8 + NW8) { src = wq; off = i - NX8; scale = 0.18033688011112042f; }  // log2e/8
    else if (i < NX8 + 2 * NW8) { src = wk; off = i - NX8 - NW8; }
    else if (i < NX8 + 3 * NW8) { src = wv; off = i - NX8 - 2 * NW8; }
    else { src = wo; off = i - NX8 - 3 * NW8; }
    const float4* p = (const float4*)src + off * 2;
    float4 a = p[0], b = p[1];
    union { uint4 u; unsigned short s[8]; } t;
    t.s[0] = f2b(a.x * scale); t.s[1] = f2b(a.y * scale);
    t.s[2] = f2b(a.z * scale); t.s[3] = f2b(a.w * scale);
    t.s[4] = f2b(b.x * scale); t.s[5] = f2b(b.y * scale);
    t.s[6] = f2b(b.z * scale); t.s[7] = f2b(b.w * scale);
    ((uint4*)out)[i] = t.u;
}

// ---------------- GEMM: C[M,N] = A[M,768] @ B[N,768]^T ----------------
// MODE 0: bf16 row-major out. MODE 1: fp32 row-major out. MODE 2: bf16
// TRANSPOSED out (C^T[N][MTOT], packed ushort4) — fuses the V-transpose.
template <int MODE>
__device__ __forceinline__ void gemm_body(const unsigned short* __restrict__ A,
                                          const unsigned short* __restrict__ Bm,
                                          float* __restrict__ Cf,
                                          unsigned short* __restrict__ Cb,
                                          int mBase, int nBase, int N) {
    __shared__ __align__(16) unsigned short Al[2][128][64];
    __shared__ __align__(16) unsigned short Bl[2][128][64];
    const int tid = threadIdx.x;
    const int lane = tid & 63;
    const int wave = tid >> 6;
    const int quad = lane >> 4;
    const int l16 = lane & 15;
    const int mw = (wave >> 1) * 64;
    const int nw = (wave & 1) * 64;
    const int srow = wave * 32 + (lane >> 3);
    const int swiz = ((lane & 7) ^ (lane >> 3)) * 8;
    const unsigned short* Asrc = A + (size_t)(mBase + srow) * HIDDEN + swiz;
    const unsigned short* Bsrc = Bm + (size_t)(nBase + srow) * HIDDEN + swiz;

    f32x4 acc[4][4];
#pragma unroll
    for (int mt = 0; mt < 4; ++mt)
#pragma unroll
        for (int nt = 0; nt < 4; ++nt) acc[mt][nt] = (f32x4){0.f, 0.f, 0.f, 0.f};

    auto stage = [&](int buf, int kb) {
#pragma unroll
        for (int i = 0; i < 4; ++i) {
            gload16(Asrc + (size_t)i * 8 * HIDDEN + kb * 64, &Al[buf][wave * 32 + i * 8][0]);
            gload16(Bsrc + (size_t)i * 8 * HIDDEN + kb * 64, &Bl[buf][wave * 32 + i * 8][0]);
        }
    };

    stage(0, 0);
    for (int kb = 0; kb < HIDDEN / 64; ++kb) {
        __syncthreads();
        if (kb + 1 < HIDDEN / 64) stage((kb + 1) & 1, kb + 1);
        const int buf = kb & 1;
#pragma unroll
        for (int ks = 0; ks < 2; ++ks) {
            const int cc = ((ks * 4 + quad) ^ (l16 & 7)) * 8;
            bf16x8 af[4], bf[4];
#pragma unroll
            for (int t = 0; t < 4; ++t) {
                af[t] = *(const bf16x8*)&Al[buf][mw + t * 16 + l16][cc];
                bf[t] = *(const bf16x8*)&Bl[buf][nw + t * 16 + l16][cc];
            }
#pragma unroll
            for (int mt = 0; mt < 4; ++mt)
#pragma unroll
                for (int nt = 0; nt < 4; ++nt)
                    acc[mt][nt] = __builtin_amdgcn_mfma_f32_16x16x32_bf16(
                        af[mt], bf[nt], acc[mt][nt], 0, 0, 0);
        }
    }

#pragma unroll
    for (int mt = 0; mt < 4; ++mt)
#pragma unroll
        for (int nt = 0; nt < 4; ++nt) {
            if (MODE == 2) {
                // transposed pack: 4 consecutive m per lane -> one ushort4
                ushort4 h;
                h.x = f2b(acc[mt][nt][0]); h.y = f2b(acc[mt][nt][1]);
                h.z = f2b(acc[mt][nt][2]); h.w = f2b(acc[mt][nt][3]);
                int m0 = mBase + mw + mt * 16 + quad * 4;
                int col = nBase + nw + nt * 16 + l16;
                *(ushort4*)&Cb[(size_t)col * MTOT + m0] = h;
            } else {
#pragma unroll
                for (int r = 0; r < 4; ++r) {
                    int row = mBase + mw + mt * 16 + quad * 4 + r;
                    int col = nBase + nw + nt * 16 + l16;
                    float v = acc[mt][nt][r];
                    if (MODE == 1)
                        Cf[(size_t)row * N + col] = v;
                    else
                        Cb[(size_t)row * N + col] = f2b(v);
                }
            }
        }
}

// Fused QKV: blockIdx.x = wsel*6 + nb. wsel 0/1 -> Q/K row-major; wsel 2 -> V
// written directly TRANSPOSED to VT (vt_kernel eliminated).
__global__ __launch_bounds__(256) void gemm_qkv(const unsigned short* __restrict__ A,
                                                const unsigned short* __restrict__ W0,
                                                unsigned short* __restrict__ C0,
                                                unsigned short* __restrict__ VT) {
    const int wsel = blockIdx.x / 6;
    const int nb = blockIdx.x % 6;
    if (wsel < 2)
        gemm_body<0>(A, W0 + (size_t)wsel * HIDDEN * HIDDEN, nullptr,
                     C0 + (size_t)wsel * MTOT * HIDDEN, blockIdx.y * 128, nb * 128, HIDDEN);
    else
        gemm_body<2>(A, W0 + 2 * (size_t)HIDDEN * HIDDEN, nullptr, VT,
                     blockIdx.y * 128, nb * 128, HIDDEN);
}

__global__ __launch_bounds__(256) void gemm_out(const unsigned short* __restrict__ A,
                                                const unsigned short* __restrict__ Bm,
                                                float* __restrict__ Cf) {
    gemm_body<1>(A, Bm, Cf, nullptr, blockIdx.y * 128, blockIdx.x * 128, HIDDEN);
}

// ---------------- Flash attention ----------------
// 4 waves x 32 q-rows. K/V double-buffered swizzled global_load_lds (1
// barrier/tile, prefetch in flight across it). S computed TRANSPOSED
// (mfma(kf,qf)): a lane's 4 C-regs = 4 consecutive keys of one q-row, so
// P hits LDS as 8 packed ds_write_b64 (+16 v_perm) instead of 32 b16 stores.
// pf/PV/lacc/epilogue layouts unchanged from r5 (verified mapping).
__global__ __launch_bounds__(256) void attn_kernel(const unsigned short* __restrict__ Qg,
                                                   const unsigned short* __restrict__ Kg,
                                                   const unsigned short* __restrict__ VTg,
                                                   unsigned short* __restrict__ Ctx) {
    __shared__ __align__(16) unsigned short Kl[2][64][64];
    __shared__ __align__(16) unsigned short Vl[2][64][64];
    __shared__ __align__(16) unsigned int Pl[4][32][36];  // [wave][q][64 keys bf16 + pad]
    const int tid = threadIdx.x;
    const int lane = tid & 63;
    const int wave = tid >> 6;
    const int quad = lane >> 4;
    const int l16 = lane & 15;
    const int qt = blockIdx.x;  // 0..15
    const int bh = blockIdx.y;  // 0..47
    const int b = bh / NH, h = bh % NH;
    const int qrow0 = b * TT + qt * 128;
    const int col0 = h * DH;

    const int srow = wave * 16 + (lane >> 3);
    const int swiz = ((lane & 7) ^ (lane >> 3)) * 8;
    const unsigned short* Ksrc = Kg + (size_t)(b * TT + srow) * HIDDEN + col0 + swiz;
    const unsigned short* Vsrc = VTg + (size_t)(col0 + srow) * MTOT + b * TT + swiz;

    auto stage = [&](int buf, int kt) {
#pragma unroll
        for (int i = 0; i < 2; ++i) {
            gload16(Ksrc + (size_t)(kt * 64 + i * 8) * HIDDEN, &Kl[buf][wave * 16 + i * 8][0]);
            gload16(Vsrc + (size_t)(i * 8) * MTOT + kt * 64, &Vl[buf][wave * 16 + i * 8][0]);
        }
    };

    // Q fragments resident all kernel (log2e/8 pre-folded into w_q)
    bf16x8 qf[2][2];
#pragma unroll
    for (int mt = 0; mt < 2; ++mt)
#pragma unroll
        for (int ks = 0; ks < 2; ++ks)
            qf[mt][ks] = *(const bf16x8*)&Qg[(size_t)(qrow0 + wave * 32 + mt * 16 + l16) * HIDDEN +
                                             col0 + ks * 32 + quad * 8];

    s16x8 osv;
#pragma unroll
    for (int e = 0; e < 8; ++e) osv[e] = 0x3F80;  // bf16 1.0
    const bf16x8 ones = __builtin_bit_cast(bf16x8, osv);

    f32x4 o[2][4];
    f32x4 lacc[2];
#pragma unroll
    for (int mt = 0; mt < 2; ++mt) {
        lacc[mt] = (f32x4){0.f, 0.f, 0.f, 0.f};
#pragma unroll
        for (int nt = 0; nt < 4; ++nt) o[mt][nt] = (f32x4){0.f, 0.f, 0.f, 0.f};
    }

    stage(0, 0);
    for (int kt = 0; kt < TT / 64; ++kt) {
        __syncthreads();  // drains only loads issued a full compute phase ago
        if (kt + 1 < TT / 64) stage((kt + 1) & 1, kt + 1);
        const int buf = kt & 1;

        // S^T = K' Q^T : lane holds key = nt*16+quad*4+r, q = mt*16+l16
        f32x4 s[2][4];
#pragma unroll
        for (int mt = 0; mt < 2; ++mt)
#pragma unroll
            for (int nt = 0; nt < 4; ++nt) s[mt][nt] = (f32x4){0.f, 0.f, 0.f, 0.f};
#pragma unroll
        for (int ks = 0; ks < 2; ++ks) {
            const int cc = ((ks * 4 + quad) ^ (l16 & 7)) * 8;
            bf16x8 kf[4];
#pragma unroll
            for (int nt = 0; nt < 4; ++nt)
                kf[nt] = *(const bf16x8*)&Kl[buf][nt * 16 + l16][cc];
#pragma unroll
            for (int mt = 0; mt < 2; ++mt)
#pragma unroll
                for (int nt = 0; nt < 4; ++nt)
                    s[mt][nt] = __builtin_amdgcn_mfma_f32_16x16x32_bf16(kf[nt], qf[mt][ks],
                                                                        s[mt][nt], 0, 0, 0);
        }

        // P = exp2(S), pack 4 consecutive keys -> one ds_write_b64
#pragma unroll
        for (int mt = 0; mt < 2; ++mt) {
            const int row = mt * 16 + l16;
#pragma unroll
            for (int nt = 0; nt < 4; ++nt) {
                float p0 = __builtin_amdgcn_exp2f(s[mt][nt][0]);
                float p1 = __builtin_amdgcn_exp2f(s[mt][nt][1]);
                float p2 = __builtin_amdgcn_exp2f(s[mt][nt][2]);
                float p3 = __builtin_amdgcn_exp2f(s[mt][nt][3]);
                uint2 w;
                w.x = pack_bf16(p0, p1);
                w.y = pack_bf16(p2, p3);
                *(uint2*)&Pl[wave][row][nt * 8 + quad * 2] = w;
            }
        }

        // O += P V ; l += P . 1   (same-wave LDS round trip: lgkmcnt only)
#pragma unroll
        for (int ks = 0; ks < 2; ++ks) {
            const int cc = ((ks * 4 + quad) ^ (l16 & 7)) * 8;
            bf16x8 pf[2], vf[4];
#pragma unroll
            for (int mt = 0; mt < 2; ++mt)
                pf[mt] = *(const bf16x8*)((const unsigned short*)&Pl[wave][mt * 16 + l16][0] +
                                          ks * 32 + quad * 8);
#pragma unroll
            for (int nt = 0; nt < 4; ++nt)
                vf[nt] = *(const bf16x8*)&Vl[buf][nt * 16 + l16][cc];
#pragma unroll
            for (int mt = 0; mt < 2; ++mt)
                lacc[mt] = __builtin_amdgcn_mfma_f32_16x16x32_bf16(pf[mt], ones, lacc[mt], 0, 0, 0);
#pragma unroll
            for (int mt = 0; mt < 2; ++mt)
#pragma unroll
                for (int nt = 0; nt < 4; ++nt)
                    o[mt][nt] = __builtin_amdgcn_mfma_f32_16x16x32_bf16(pf[mt], vf[nt],
                                                                        o[mt][nt], 0, 0, 0);
        }
    }

    // Epilogue: normalize by MFMA row sums (C-layout, no shuffles)
#pragma unroll
    for (int mt = 0; mt < 2; ++mt)
#pragma unroll
        for (int r = 0; r < 4; ++r) {
            float inv = __builtin_amdgcn_rcpf(lacc[mt][r]);
            int row = qrow0 + wave * 32 + mt * 16 + quad * 4 + r;
#pragma unroll
            for (int nt = 0; nt < 4; ++nt)
                Ctx[(size_t)row * HIDDEN + col0 + nt * 16 + l16] = f2b(o[mt][nt][r] * inv);
        }
}

// ---------------- launch ----------------
extern "C" void kernel_launch(void* const* d_in, const int* in_sizes, int n_in,
                              void* d_out, int out_size, void* d_ws, size_t ws_size,
                              hipStream_t stream) {
    const float* x = (const float*)d_in[0];
    const float* wq = (const float*)d_in[1];
    const float* wk = (const float*)d_in[2];
    const float* wv = (const float*)d_in[3];
    const float* wo = (const float*)d_in[4];
    float* out = (float*)d_out;

    const size_t NX = (size_t)MTOT * HIDDEN;
    const size_t NW = (size_t)HIDDEN * HIDDEN;
    unsigned short* ws = (unsigned short*)d_ws;
    unsigned short* xb = ws;            // cvt_all writes x|wq|wk|wv|wo contiguously
    unsigned short* wqb = xb + NX;
    unsigned short* wob = wqb + 3 * NW;
    unsigned short* qb = wob + NW;      // q|k contiguous (fused GEMM output)
    unsigned short* kb = qb + NX;
    unsigned short* cb = kb + NX;       // ctx (region formerly vb)
    unsigned short* vtb = cb + NX;      // V^T written directly by gemm_qkv

    cvt_all<<<(int)((NX + 4 * NW) / 8 / 256), 256, 0, stream>>>(x, wq, wk, wv, wo, xb);

    gemm_qkv<<<dim3(18, MTOT / 128), 256, 0, stream>>>(xb, wqb, qb, vtb);

    attn_kernel<<<dim3(TT / 128, BB * NH), 256, 0, stream>>>(qb, kb, vtb, cb);

    gemm_out<<<dim3(6, MTOT / 128), 256, 0, stream>>>(cb, wob, out);
}

// Round 7
// 220.452 us; speedup vs baseline: 1.7531x; 1.0085x over previous
//
#include <hip/hip_runtime.h>

#define HIDDEN 768
#define NH 12
#define DH 64
#define BB 4
#define TT 2048
#define MTOT (BB * TT)  // 8192

typedef __bf16 bf16x8 __attribute__((ext_vector_type(8)));
typedef short s16x8 __attribute__((ext_vector_type(8)));
typedef float f32x4 __attribute__((ext_vector_type(4)));

__device__ __forceinline__ unsigned short f2b(float f) {
    unsigned u = __builtin_bit_cast(unsigned, f);
    u += 0x7fffu + ((u >> 16) & 1u);  // RNE
    return (unsigned short)(u >> 16);
}

// pack two f32 -> (bf16(lo)=trunc(a), bf16(hi)=trunc(b)) in one v_perm_b32
__device__ __forceinline__ unsigned pack_bf16(float a, float b) {
    return __builtin_amdgcn_perm(__builtin_bit_cast(unsigned, b),
                                 __builtin_bit_cast(unsigned, a), 0x07060302u);
}

typedef const __attribute__((address_space(1))) unsigned int* gas_ptr;
typedef __attribute__((address_space(3))) unsigned int* las_ptr;
__device__ __forceinline__ void gload16(const void* g, void* l) {
    // DMA: lane i lands at (wave-uniform) lds base + i*16.
    __builtin_amdgcn_global_load_lds((gas_ptr)(uintptr_t)g, (las_ptr)(uintptr_t)l, 16, 0, 0);
}

// ---------------- fused fp32->bf16 for all 5 tensors (1 launch) ----------------
__global__ __launch_bounds__(256) void cvt_all(const float* __restrict__ x,
                                               const float* __restrict__ wq,
                                               const float* __restrict__ wk,
                                               const float* __restrict__ wv,
                                               const float* __restrict__ wo,
                                               unsigned short* __restrict__ out) {
    const size_t NX8 = (size_t)MTOT * HIDDEN / 8;
    const size_t NW8 = (size_t)HIDDEN * HIDDEN / 8;
    size_t i = (size_t)blockIdx.x * 256 + threadIdx.x;
    const float* src;
    size_t off = i;
    float scale = 1.0f;
    if (i < NX8) { src = x; }
    else if (i < NX8 + NW8) { src = wq; off = i - NX8; scale = 0.18033688011112042f; }  // log2e/8
    else if (i < NX8 + 2 * NW8) { src = wk; off = i - NX8 - NW8; }
    else if (i < NX8 + 3 * NW8) { src = wv; off = i - NX8 - 2 * NW8; }
    else { src = wo; off = i - NX8 - 3 * NW8; }
    const float4* p = (const float4*)src + off * 2;
    float4 a = p[0], b = p[1];
    union { uint4 u; unsigned short s[8]; } t;
    t.s[0] = f2b(a.x * scale); t.s[1] = f2b(a.y * scale);
    t.s[2] = f2b(a.z * scale); t.s[3] = f2b(a.w * scale);
    t.s[4] = f2b(b.x * scale); t.s[5] = f2b(b.y * scale);
    t.s[6] = f2b(b.z * scale); t.s[7] = f2b(b.w * scale);
    ((uint4*)out)[i] = t.u;
}

// ---------------- GEMM: C[M,N] = A[M,768] @ B[N,768]^T ----------------
// MROWS x 128 tile, SINGLE-buffered (m97 2-barrier K-loop): LDS 32 KB (24 KB
// for MROWS=64) -> 4 blocks/CU (VGPR-capped via __launch_bounds__(256,4)),
// double r6's occupancy. gload16 DMA staging, XOR chunk swizzle
// (LDS[row][c]=glob[row][c^(row&7)]) -> b128 fragment reads at bank floor.
// MODE 0: bf16 out; 1: fp32 out; 2: bf16 transposed out (fused V-transpose).
template <int MODE, int MROWS>
__device__ __forceinline__ void gemm_body(const unsigned short* __restrict__ A,
                                          const unsigned short* __restrict__ Bm,
                                          float* __restrict__ Cf,
                                          unsigned short* __restrict__ Cb,
                                          int mBase, int nBase, int N) {
    __shared__ __align__(16) unsigned short Al[MROWS][64];
    __shared__ __align__(16) unsigned short Bl[128][64];
    const int MT = MROWS / 32;  // m-tiles per wave
    const int tid = threadIdx.x;
    const int lane = tid & 63;
    const int wave = tid >> 6;
    const int quad = lane >> 4;
    const int l16 = lane & 15;
    const int mw = (wave >> 1) * (MROWS / 2);
    const int nw = (wave & 1) * 64;
    const int r8 = lane >> 3;
    const int swiz = ((lane & 7) ^ r8) * 8;
    const unsigned short* Asrc = A + (size_t)(mBase + wave * (MROWS / 4) + r8) * HIDDEN + swiz;
    const unsigned short* Bsrc = Bm + (size_t)(nBase + wave * 32 + r8) * HIDDEN + swiz;

    f32x4 acc[MT][4];
#pragma unroll
    for (int mt = 0; mt < MT; ++mt)
#pragma unroll
        for (int nt = 0; nt < 4; ++nt) acc[mt][nt] = (f32x4){0.f, 0.f, 0.f, 0.f};

    for (int kb = 0; kb < HIDDEN / 64; ++kb) {
        if (kb) __syncthreads();  // all waves done reading previous tile
#pragma unroll
        for (int i = 0; i < MROWS / 32; ++i)
            gload16(Asrc + (size_t)i * 8 * HIDDEN + kb * 64,
                    &Al[wave * (MROWS / 4) + i * 8][0]);
#pragma unroll
        for (int j = 0; j < 4; ++j)
            gload16(Bsrc + (size_t)j * 8 * HIDDEN + kb * 64, &Bl[wave * 32 + j * 8][0]);
        __syncthreads();  // staging complete (vmcnt drain)
#pragma unroll
        for (int ks = 0; ks < 2; ++ks) {
            const int cc = ((ks * 4 + quad) ^ (l16 & 7)) * 8;
            bf16x8 af[MT], bf[4];
#pragma unroll
            for (int mt = 0; mt < MT; ++mt)
                af[mt] = *(const bf16x8*)&Al[mw + mt * 16 + l16][cc];
#pragma unroll
            for (int nt = 0; nt < 4; ++nt)
                bf[nt] = *(const bf16x8*)&Bl[nw + nt * 16 + l16][cc];
#pragma unroll
            for (int mt = 0; mt < MT; ++mt)
#pragma unroll
                for (int nt = 0; nt < 4; ++nt)
                    acc[mt][nt] = __builtin_amdgcn_mfma_f32_16x16x32_bf16(
                        af[mt], bf[nt], acc[mt][nt], 0, 0, 0);
        }
    }

#pragma unroll
    for (int mt = 0; mt < MT; ++mt)
#pragma unroll
        for (int nt = 0; nt < 4; ++nt) {
            if (MODE == 2) {
                // transposed pack: 4 consecutive m per lane -> one ushort4
                ushort4 h;
                h.x = f2b(acc[mt][nt][0]); h.y = f2b(acc[mt][nt][1]);
                h.z = f2b(acc[mt][nt][2]); h.w = f2b(acc[mt][nt][3]);
                int m0 = mBase + mw + mt * 16 + quad * 4;
                int col = nBase + nw + nt * 16 + l16;
                *(ushort4*)&Cb[(size_t)col * MTOT + m0] = h;
            } else {
#pragma unroll
                for (int r = 0; r < 4; ++r) {
                    int row = mBase + mw + mt * 16 + quad * 4 + r;
                    int col = nBase + nw + nt * 16 + l16;
                    float v = acc[mt][nt][r];
                    if (MODE == 1)
                        Cf[(size_t)row * N + col] = v;
                    else
                        Cb[(size_t)row * N + col] = f2b(v);
                }
            }
        }
}

// Fused QKV: blockIdx.x = wsel*6 + nb. wsel 0/1 -> Q/K row-major; wsel 2 -> V
// written directly TRANSPOSED to VT.
__global__ __launch_bounds__(256, 4) void gemm_qkv(const unsigned short* __restrict__ A,
                                                   const unsigned short* __restrict__ W0,
                                                   unsigned short* __restrict__ C0,
                                                   unsigned short* __restrict__ VT) {
    const int wsel = blockIdx.x / 6;
    const int nb = blockIdx.x % 6;
    if (wsel < 2)
        gemm_body<0, 128>(A, W0 + (size_t)wsel * HIDDEN * HIDDEN, nullptr,
                          C0 + (size_t)wsel * MTOT * HIDDEN, blockIdx.y * 128, nb * 128, HIDDEN);
    else
        gemm_body<2, 128>(A, W0 + 2 * (size_t)HIDDEN * HIDDEN, nullptr, VT,
                          blockIdx.y * 128, nb * 128, HIDDEN);
}

// 64x128 tiles: grid 768 = exactly 3 blocks/CU (fixes the 384-block imbalance).
__global__ __launch_bounds__(256, 4) void gemm_out(const unsigned short* __restrict__ A,
                                                   const unsigned short* __restrict__ Bm,
                                                   float* __restrict__ Cf) {
    gemm_body<1, 64>(A, Bm, Cf, nullptr, blockIdx.y * 64, blockIdx.x * 128, HIDDEN);
}

// ---------------- Flash attention (unchanged from r6) ----------------
__global__ __launch_bounds__(256) void attn_kernel(const unsigned short* __restrict__ Qg,
                                                   const unsigned short* __restrict__ Kg,
                                                   const unsigned short* __restrict__ VTg,
                                                   unsigned short* __restrict__ Ctx) {
    __shared__ __align__(16) unsigned short Kl[2][64][64];
    __shared__ __align__(16) unsigned short Vl[2][64][64];
    __shared__ __align__(16) unsigned int Pl[4][32][36];  // [wave][q][64 keys bf16 + pad]
    const int tid = threadIdx.x;
    const int lane = tid & 63;
    const int wave = tid >> 6;
    const int quad = lane >> 4;
    const int l16 = lane & 15;
    const int qt = blockIdx.x;  // 0..15
    const int bh = blockIdx.y;  // 0..47
    const int b = bh / NH, h = bh % NH;
    const int qrow0 = b * TT + qt * 128;
    const int col0 = h * DH;

    const int srow = wave * 16 + (lane >> 3);
    const int swiz = ((lane & 7) ^ (lane >> 3)) * 8;
    const unsigned short* Ksrc = Kg + (size_t)(b * TT + srow) * HIDDEN + col0 + swiz;
    const unsigned short* Vsrc = VTg + (size_t)(col0 + srow) * MTOT + b * TT + swiz;

    auto stage = [&](int buf, int kt) {
#pragma unroll
        for (int i = 0; i < 2; ++i) {
            gload16(Ksrc + (size_t)(kt * 64 + i * 8) * HIDDEN, &Kl[buf][wave * 16 + i * 8][0]);
            gload16(Vsrc + (size_t)(i * 8) * MTOT + kt * 64, &Vl[buf][wave * 16 + i * 8][0]);
        }
    };

    // Q fragments resident all kernel (log2e/8 pre-folded into w_q)
    bf16x8 qf[2][2];
#pragma unroll
    for (int mt = 0; mt < 2; ++mt)
#pragma unroll
        for (int ks = 0; ks < 2; ++ks)
            qf[mt][ks] = *(const bf16x8*)&Qg[(size_t)(qrow0 + wave * 32 + mt * 16 + l16) * HIDDEN +
                                             col0 + ks * 32 + quad * 8];

    s16x8 osv;
#pragma unroll
    for (int e = 0; e < 8; ++e) osv[e] = 0x3F80;  // bf16 1.0
    const bf16x8 ones = __builtin_bit_cast(bf16x8, osv);

    f32x4 o[2][4];
    f32x4 lacc[2];
#pragma unroll
    for (int mt = 0; mt < 2; ++mt) {
        lacc[mt] = (f32x4){0.f, 0.f, 0.f, 0.f};
#pragma unroll
        for (int nt = 0; nt < 4; ++nt) o[mt][nt] = (f32x4){0.f, 0.f, 0.f, 0.f};
    }

    stage(0, 0);
    for (int kt = 0; kt < TT / 64; ++kt) {
        __syncthreads();  // drains only loads issued a full compute phase ago
        if (kt + 1 < TT / 64) stage((kt + 1) & 1, kt + 1);
        const int buf = kt & 1;

        // S^T = K' Q^T : lane holds key = nt*16+quad*4+r, q = mt*16+l16
        f32x4 s[2][4];
#pragma unroll
        for (int mt = 0; mt < 2; ++mt)
#pragma unroll
            for (int nt = 0; nt < 4; ++nt) s[mt][nt] = (f32x4){0.f, 0.f, 0.f, 0.f};
#pragma unroll
        for (int ks = 0; ks < 2; ++ks) {
            const int cc = ((ks * 4 + quad) ^ (l16 & 7)) * 8;
            bf16x8 kf[4];
#pragma unroll
            for (int nt = 0; nt < 4; ++nt)
                kf[nt] = *(const bf16x8*)&Kl[buf][nt * 16 + l16][cc];
#pragma unroll
            for (int mt = 0; mt < 2; ++mt)
#pragma unroll
                for (int nt = 0; nt < 4; ++nt)
                    s[mt][nt] = __builtin_amdgcn_mfma_f32_16x16x32_bf16(kf[nt], qf[mt][ks],
                                                                        s[mt][nt], 0, 0, 0);
        }

        // P = exp2(S), pack 4 consecutive keys -> one ds_write_b64
#pragma unroll
        for (int mt = 0; mt < 2; ++mt) {
            const int row = mt * 16 + l16;
#pragma unroll
            for (int nt = 0; nt < 4; ++nt) {
                float p0 = __builtin_amdgcn_exp2f(s[mt][nt][0]);
                float p1 = __builtin_amdgcn_exp2f(s[mt][nt][1]);
                float p2 = __builtin_amdgcn_exp2f(s[mt][nt][2]);
                float p3 = __builtin_amdgcn_exp2f(s[mt][nt][3]);
                uint2 w;
                w.x = pack_bf16(p0, p1);
                w.y = pack_bf16(p2, p3);
                *(uint2*)&Pl[wave][row][nt * 8 + quad * 2] = w;
            }
        }

        // O += P V ; l += P . 1   (same-wave LDS round trip: lgkmcnt only)
#pragma unroll
        for (int ks = 0; ks < 2; ++ks) {
            const int cc = ((ks * 4 + quad) ^ (l16 & 7)) * 8;
            bf16x8 pf[2], vf[4];
#pragma unroll
            for (int mt = 0; mt < 2; ++mt)
                pf[mt] = *(const bf16x8*)((const unsigned short*)&Pl[wave][mt * 16 + l16][0] +
                                          ks * 32 + quad * 8);
#pragma unroll
            for (int nt = 0; nt < 4; ++nt)
                vf[nt] = *(const bf16x8*)&Vl[buf][nt * 16 + l16][cc];
#pragma unroll
            for (int mt = 0; mt < 2; ++mt)
                lacc[mt] = __builtin_amdgcn_mfma_f32_16x16x32_bf16(pf[mt], ones, lacc[mt], 0, 0, 0);
#pragma unroll
            for (int mt = 0; mt < 2; ++mt)
#pragma unroll
                for (int nt = 0; nt < 4; ++nt)
                    o[mt][nt] = __builtin_amdgcn_mfma_f32_16x16x32_bf16(pf[mt], vf[nt],
                                                                        o[mt][nt], 0, 0, 0);
        }
    }

    // Epilogue: normalize by MFMA row sums (C-layout, no shuffles)
#pragma unroll
    for (int mt = 0; mt < 2; ++mt)
#pragma unroll
        for (int r = 0; r < 4; ++r) {
            float inv = __builtin_amdgcn_rcpf(lacc[mt][r]);
            int row = qrow0 + wave * 32 + mt * 16 + quad * 4 + r;
#pragma unroll
            for (int nt = 0; nt < 4; ++nt)
                Ctx[(size_t)row * HIDDEN + col0 + nt * 16 + l16] = f2b(o[mt][nt][r] * inv);
        }
}

// ---------------- launch ----------------
extern "C" void kernel_launch(void* const* d_in, const int* in_sizes, int n_in,
                              void* d_out, int out_size, void* d_ws, size_t ws_size,
                              hipStream_t stream) {
    const float* x = (const float*)d_in[0];
    const float* wq = (const float*)d_in[1];
    const float* wk = (const float*)d_in[2];
    const float* wv = (const float*)d_in[3];
    const float* wo = (const float*)d_in[4];
    float* out = (float*)d_out;

    const size_t NX = (size_t)MTOT * HIDDEN;
    const size_t NW = (size_t)HIDDEN * HIDDEN;
    unsigned short* ws = (unsigned short*)d_ws;
    unsigned short* xb = ws;            // cvt_all writes x|wq|wk|wv|wo contiguously
    unsigned short* wqb = xb + NX;
    unsigned short* wob = wqb + 3 * NW;
    unsigned short* qb = wob + NW;      // q|k contiguous (fused GEMM output)
    unsigned short* kb = qb + NX;
    unsigned short* cb = kb + NX;       // ctx
    unsigned short* vtb = cb + NX;      // V^T written directly by gemm_qkv

    cvt_all<<<(int)((NX + 4 * NW) / 8 / 256), 256, 0, stream>>>(x, wq, wk, wv, wo, xb);

    gemm_qkv<<<dim3(18, MTOT / 128), 256, 0, stream>>>(xb, wqb, qb, vtb);

    attn_kernel<<<dim3(TT / 128, BB * NH), 256, 0, stream>>>(qb, kb, vtb, cb);

    gemm_out<<<dim3(6, MTOT / 64), 256, 0, stream>>>(cb, wob, out);
}

// Round 8
// 216.365 us; speedup vs baseline: 1.7862x; 1.0189x over previous
//
#include <hip/hip_runtime.h>

#define HIDDEN 768
#define NH 12
#define DH 64
#define BB 4
#define TT 2048
#define MTOT (BB * TT)  // 8192

typedef __bf16 bf16x8 __attribute__((ext_vector_type(8)));
typedef short s16x8 __attribute__((ext_vector_type(8)));
typedef float f32x4 __attribute__((ext_vector_type(4)));

__device__ __forceinline__ unsigned short f2b(float f) {
    unsigned u = __builtin_bit_cast(unsigned, f);
    u += 0x7fffu + ((u >> 16) & 1u);  // RNE
    return (unsigned short)(u >> 16);
}

// pack two f32 -> (bf16(lo)=trunc(a), bf16(hi)=trunc(b)) in one v_perm_b32
__device__ __forceinline__ unsigned pack_bf16(float a, float b) {
    return __builtin_amdgcn_perm(__builtin_bit_cast(unsigned, b),
                                 __builtin_bit_cast(unsigned, a), 0x07060302u);
}

typedef const __attribute__((address_space(1))) unsigned int* gas_ptr;
typedef __attribute__((address_space(3))) unsigned int* las_ptr;
__device__ __forceinline__ void gload16(const void* g, void* l) {
    // DMA: lane i lands at (wave-uniform) lds base + i*16.
    __builtin_amdgcn_global_load_lds((gas_ptr)(uintptr_t)g, (las_ptr)(uintptr_t)l, 16, 0, 0);
}

// ---------------- fused fp32->bf16 for all 5 tensors (1 launch) ----------------
__global__ __launch_bounds__(256) void cvt_all(const float* __restrict__ x,
                                               const float* __restrict__ wq,
                                               const float* __restrict__ wk,
                                               const float* __restrict__ wv,
                                               const float* __restrict__ wo,
                                               unsigned short* __restrict__ out) {
    const size_t NX8 = (size_t)MTOT * HIDDEN / 8;
    const size_t NW8 = (size_t)HIDDEN * HIDDEN / 8;
    size_t i = (size_t)blockIdx.x * 256 + threadIdx.x;
    const float* src;
    size_t off = i;
    float scale = 1.0f;
    if (i < NX8) { src = x; }
    else if (i < NX8 + NW8) { src = wq; off = i - NX8; scale = 0.18033688011112042f; }  // log2e/8
    else if (i < NX8 + 2 * NW8) { src = wk; off = i - NX8 - NW8; }
    else if (i < NX8 + 3 * NW8) { src = wv; off = i - NX8 - 2 * NW8; }
    else { src = wo; off = i - NX8 - 3 * NW8; }
    const float4* p = (const float4*)src + off * 2;
    float4 a = p[0], b = p[1];
    union { uint4 u; unsigned short s[8]; } t;
    t.s[0] = f2b(a.x * scale); t.s[1] = f2b(a.y * scale);
    t.s[2] = f2b(a.z * scale); t.s[3] = f2b(a.w * scale);
    t.s[4] = f2b(b.x * scale); t.s[5] = f2b(b.y * scale);
    t.s[6] = f2b(b.z * scale); t.s[7] = f2b(b.w * scale);
    ((uint4*)out)[i] = t.u;
}

// ---------------- GEMM: C[M,N] = A[M,768] @ B[N,768]^T ----------------
// MROWS x 128 tile, single-buffered m97 2-barrier K-loop, gload16 DMA staging,
// XOR chunk swizzle. MODE 0: bf16 out; 1: fp32 out; 2: bf16 transposed out.
template <int MODE, int MROWS>
__device__ __forceinline__ void gemm_body(const unsigned short* __restrict__ A,
                                          const unsigned short* __restrict__ Bm,
                                          float* __restrict__ Cf,
                                          unsigned short* __restrict__ Cb,
                                          int mBase, int nBase, int N) {
    __shared__ __align__(16) unsigned short Al[MROWS][64];
    __shared__ __align__(16) unsigned short Bl[128][64];
    const int MT = MROWS / 32;  // m-tiles per wave
    const int tid = threadIdx.x;
    const int lane = tid & 63;
    const int wave = tid >> 6;
    const int quad = lane >> 4;
    const int l16 = lane & 15;
    const int mw = (wave >> 1) * (MROWS / 2);
    const int nw = (wave & 1) * 64;
    const int r8 = lane >> 3;
    const int swiz = ((lane & 7) ^ r8) * 8;
    const unsigned short* Asrc = A + (size_t)(mBase + wave * (MROWS / 4) + r8) * HIDDEN + swiz;
    const unsigned short* Bsrc = Bm + (size_t)(nBase + wave * 32 + r8) * HIDDEN + swiz;

    f32x4 acc[MT][4];
#pragma unroll
    for (int mt = 0; mt < MT; ++mt)
#pragma unroll
        for (int nt = 0; nt < 4; ++nt) acc[mt][nt] = (f32x4){0.f, 0.f, 0.f, 0.f};

    for (int kb = 0; kb < HIDDEN / 64; ++kb) {
        if (kb) __syncthreads();  // all waves done reading previous tile
#pragma unroll
        for (int i = 0; i < MROWS / 32; ++i)
            gload16(Asrc + (size_t)i * 8 * HIDDEN + kb * 64,
                    &Al[wave * (MROWS / 4) + i * 8][0]);
#pragma unroll
        for (int j = 0; j < 4; ++j)
            gload16(Bsrc + (size_t)j * 8 * HIDDEN + kb * 64, &Bl[wave * 32 + j * 8][0]);
        __syncthreads();  // staging complete (vmcnt drain)
#pragma unroll
        for (int ks = 0; ks < 2; ++ks) {
            const int cc = ((ks * 4 + quad) ^ (l16 & 7)) * 8;
            bf16x8 af[MT], bf[4];
#pragma unroll
            for (int mt = 0; mt < MT; ++mt)
                af[mt] = *(const bf16x8*)&Al[mw + mt * 16 + l16][cc];
#pragma unroll
            for (int nt = 0; nt < 4; ++nt)
                bf[nt] = *(const bf16x8*)&Bl[nw + nt * 16 + l16][cc];
#pragma unroll
            for (int mt = 0; mt < MT; ++mt)
#pragma unroll
                for (int nt = 0; nt < 4; ++nt)
                    acc[mt][nt] = __builtin_amdgcn_mfma_f32_16x16x32_bf16(
                        af[mt], bf[nt], acc[mt][nt], 0, 0, 0);
        }
    }

#pragma unroll
    for (int mt = 0; mt < MT; ++mt)
#pragma unroll
        for (int nt = 0; nt < 4; ++nt) {
            if (MODE == 2) {
                // transposed pack: 4 consecutive m per lane -> one ushort4
                ushort4 h;
                h.x = f2b(acc[mt][nt][0]); h.y = f2b(acc[mt][nt][1]);
                h.z = f2b(acc[mt][nt][2]); h.w = f2b(acc[mt][nt][3]);
                int m0 = mBase + mw + mt * 16 + quad * 4;
                int col = nBase + nw + nt * 16 + l16;
                *(ushort4*)&Cb[(size_t)col * MTOT + m0] = h;
            } else {
#pragma unroll
                for (int r = 0; r < 4; ++r) {
                    int row = mBase + mw + mt * 16 + quad * 4 + r;
                    int col = nBase + nw + nt * 16 + l16;
                    float v = acc[mt][nt][r];
                    if (MODE == 1)
                        Cf[(size_t)row * N + col] = v;
                    else
                        Cb[(size_t)row * N + col] = f2b(v);
                }
            }
        }
}

// XCD-aware grids (linear id % 8 = XCD): m-tile in blockIdx.x with grid.x a
// multiple of 8 keeps all blocks sharing an A-tile on ONE XCD's L2.
// grid(64, 18): XCD = mtile % 8; the 18 (wsel,nb) blocks of an m-tile co-locate.
__global__ __launch_bounds__(256, 4) void gemm_qkv(const unsigned short* __restrict__ A,
                                                   const unsigned short* __restrict__ W0,
                                                   unsigned short* __restrict__ C0,
                                                   unsigned short* __restrict__ VT) {
    const int wsel = blockIdx.y / 6;
    const int nb = blockIdx.y % 6;
    if (wsel < 2)
        gemm_body<0, 128>(A, W0 + (size_t)wsel * HIDDEN * HIDDEN, nullptr,
                          C0 + (size_t)wsel * MTOT * HIDDEN, blockIdx.x * 128, nb * 128, HIDDEN);
    else
        gemm_body<2, 128>(A, W0 + 2 * (size_t)HIDDEN * HIDDEN, nullptr, VT,
                          blockIdx.x * 128, nb * 128, HIDDEN);
}

// grid(128, 6): XCD = mtile % 8 (128 multiple of 8); ctx-tile reuse per XCD.
__global__ __launch_bounds__(256, 4) void gemm_out(const unsigned short* __restrict__ A,
                                                   const unsigned short* __restrict__ Bm,
                                                   float* __restrict__ Cf) {
    gemm_body<1, 64>(A, Bm, Cf, nullptr, blockIdx.x * 64, blockIdx.y * 128, HIDDEN);
}

// ---------------- Flash attention ----------------
// grid(48, 16): linear id = bh + 48*qt, 48 % 8 == 0 => XCD = bh % 8 — all 16
// q-blocks of one (b,h) share one XCD's L2, so the K/V slice (512 KB) is
// fetched from HBM once per XCD instead of 8x, and steady-state staging hits
// L2 (~200 cy < compute phase => barrier drain stall gone).
__global__ __launch_bounds__(256) void attn_kernel(const unsigned short* __restrict__ Qg,
                                                   const unsigned short* __restrict__ Kg,
                                                   const unsigned short* __restrict__ VTg,
                                                   unsigned short* __restrict__ Ctx) {
    __shared__ __align__(16) unsigned short Kl[2][64][64];
    __shared__ __align__(16) unsigned short Vl[2][64][64];
    __shared__ __align__(16) unsigned int Pl[4][32][36];  // [wave][q][64 keys bf16 + pad]
    const int tid = threadIdx.x;
    const int lane = tid & 63;
    const int wave = tid >> 6;
    const int quad = lane >> 4;
    const int l16 = lane & 15;
    const int qt = blockIdx.y;  // 0..15
    const int bh = blockIdx.x;  // 0..47  (XCD = bh % 8)
    const int b = bh / NH, h = bh % NH;
    const int qrow0 = b * TT + qt * 128;
    const int col0 = h * DH;

    const int srow = wave * 16 + (lane >> 3);
    const int swiz = ((lane & 7) ^ (lane >> 3)) * 8;
    const unsigned short* Ksrc = Kg + (size_t)(b * TT + srow) * HIDDEN + col0 + swiz;
    const unsigned short* Vsrc = VTg + (size_t)(col0 + srow) * MTOT + b * TT + swiz;

    auto stage = [&](int buf, int kt) {
#pragma unroll
        for (int i = 0; i < 2; ++i) {
            gload16(Ksrc + (size_t)(kt * 64 + i * 8) * HIDDEN, &Kl[buf][wave * 16 + i * 8][0]);
            gload16(Vsrc + (size_t)(i * 8) * MTOT + kt * 64, &Vl[buf][wave * 16 + i * 8][0]);
        }
    };

    // Q fragments resident all kernel (log2e/8 pre-folded into w_q)
    bf16x8 qf[2][2];
#pragma unroll
    for (int mt = 0; mt < 2; ++mt)
#pragma unroll
        for (int ks = 0; ks < 2; ++ks)
            qf[mt][ks] = *(const bf16x8*)&Qg[(size_t)(qrow0 + wave * 32 + mt * 16 + l16) * HIDDEN +
                                             col0 + ks * 32 + quad * 8];

    s16x8 osv;
#pragma unroll
    for (int e = 0; e < 8; ++e) osv[e] = 0x3F80;  // bf16 1.0
    const bf16x8 ones = __builtin_bit_cast(bf16x8, osv);

    f32x4 o[2][4];
    f32x4 lacc[2];
#pragma unroll
    for (int mt = 0; mt < 2; ++mt) {
        lacc[mt] = (f32x4){0.f, 0.f, 0.f, 0.f};
#pragma unroll
        for (int nt = 0; nt < 4; ++nt) o[mt][nt] = (f32x4){0.f, 0.f, 0.f, 0.f};
    }

    stage(0, 0);
    for (int kt = 0; kt < TT / 64; ++kt) {
        __syncthreads();  // drains only loads issued a full compute phase ago
        if (kt + 1 < TT / 64) stage((kt + 1) & 1, kt + 1);
        const int buf = kt & 1;

        // S^T = K' Q^T : lane holds key = nt*16+quad*4+r, q = mt*16+l16
        f32x4 s[2][4];
#pragma unroll
        for (int mt = 0; mt < 2; ++mt)
#pragma unroll
            for (int nt = 0; nt < 4; ++nt) s[mt][nt] = (f32x4){0.f, 0.f, 0.f, 0.f};
#pragma unroll
        for (int ks = 0; ks < 2; ++ks) {
            const int cc = ((ks * 4 + quad) ^ (l16 & 7)) * 8;
            bf16x8 kf[4];
#pragma unroll
            for (int nt = 0; nt < 4; ++nt)
                kf[nt] = *(const bf16x8*)&Kl[buf][nt * 16 + l16][cc];
#pragma unroll
            for (int mt = 0; mt < 2; ++mt)
#pragma unroll
                for (int nt = 0; nt < 4; ++nt)
                    s[mt][nt] = __builtin_amdgcn_mfma_f32_16x16x32_bf16(kf[nt], qf[mt][ks],
                                                                        s[mt][nt], 0, 0, 0);
        }

        // P = exp2(S), pack 4 consecutive keys -> one ds_write_b64
#pragma unroll
        for (int mt = 0; mt < 2; ++mt) {
            const int row = mt * 16 + l16;
#pragma unroll
            for (int nt = 0; nt < 4; ++nt) {
                float p0 = __builtin_amdgcn_exp2f(s[mt][nt][0]);
                float p1 = __builtin_amdgcn_exp2f(s[mt][nt][1]);
                float p2 = __builtin_amdgcn_exp2f(s[mt][nt][2]);
                float p3 = __builtin_amdgcn_exp2f(s[mt][nt][3]);
                uint2 w;
                w.x = pack_bf16(p0, p1);
                w.y = pack_bf16(p2, p3);
                *(uint2*)&Pl[wave][row][nt * 8 + quad * 2] = w;
            }
        }

        // O += P V ; l += P . 1   (same-wave LDS round trip: lgkmcnt only)
#pragma unroll
        for (int ks = 0; ks < 2; ++ks) {
            const int cc = ((ks * 4 + quad) ^ (l16 & 7)) * 8;
            bf16x8 pf[2], vf[4];
#pragma unroll
            for (int mt = 0; mt < 2; ++mt)
                pf[mt] = *(const bf16x8*)((const unsigned short*)&Pl[wave][mt * 16 + l16][0] +
                                          ks * 32 + quad * 8);
#pragma unroll
            for (int nt = 0; nt < 4; ++nt)
                vf[nt] = *(const bf16x8*)&Vl[buf][nt * 16 + l16][cc];
#pragma unroll
            for (int mt = 0; mt < 2; ++mt)
                lacc[mt] = __builtin_amdgcn_mfma_f32_16x16x32_bf16(pf[mt], ones, lacc[mt], 0, 0, 0);
#pragma unroll
            for (int mt = 0; mt < 2; ++mt)
#pragma unroll
                for (int nt = 0; nt < 4; ++nt)
                    o[mt][nt] = __builtin_amdgcn_mfma_f32_16x16x32_bf16(pf[mt], vf[nt],
                                                                        o[mt][nt], 0, 0, 0);
        }
    }

    // Epilogue: normalize by MFMA row sums (C-layout, no shuffles)
#pragma unroll
    for (int mt = 0; mt < 2; ++mt)
#pragma unroll
        for (int r = 0; r < 4; ++r) {
            float inv = __builtin_amdgcn_rcpf(lacc[mt][r]);
            int row = qrow0 + wave * 32 + mt * 16 + quad * 4 + r;
#pragma unroll
            for (int nt = 0; nt < 4; ++nt)
                Ctx[(size_t)row * HIDDEN + col0 + nt * 16 + l16] = f2b(o[mt][nt][r] * inv);
        }
}

// ---------------- launch ----------------
extern "C" void kernel_launch(void* const* d_in, const int* in_sizes, int n_in,
                              void* d_out, int out_size, void* d_ws, size_t ws_size,
                              hipStream_t stream) {
    const float* x = (const float*)d_in[0];
    const float* wq = (const float*)d_in[1];
    const float* wk = (const float*)d_in[2];
    const float* wv = (const float*)d_in[3];
    const float* wo = (const float*)d_in[4];
    float* out = (float*)d_out;

    const size_t NX = (size_t)MTOT * HIDDEN;
    const size_t NW = (size_t)HIDDEN * HIDDEN;
    unsigned short* ws = (unsigned short*)d_ws;
    unsigned short* xb = ws;            // cvt_all writes x|wq|wk|wv|wo contiguously
    unsigned short* wqb = xb + NX;
    unsigned short* wob = wqb + 3 * NW;
    unsigned short* qb = wob + NW;      // q|k contiguous (fused GEMM output)
    unsigned short* kb = qb + NX;
    unsigned short* cb = kb + NX;       // ctx
    unsigned short* vtb = cb + NX;      // V^T written directly by gemm_qkv

    cvt_all<<<(int)((NX + 4 * NW) / 8 / 256), 256, 0, stream>>>(x, wq, wk, wv, wo, xb);

    gemm_qkv<<<dim3(MTOT / 128, 18), 256, 0, stream>>>(xb, wqb, qb, vtb);

    attn_kernel<<<dim3(BB * NH, TT / 128), 256, 0, stream>>>(qb, kb, vtb, cb);

    gemm_out<<<dim3(MTOT / 64, 6), 256, 0, stream>>>(cb, wob, out);
}